// Round 2
// baseline (91.396 us; speedup 1.0000x reference)
//
#include <hip/hip_runtime.h>
#include <math.h>

#define G_ 320
#define N_ 1000
#define T_ 10
#define C_ 96
#define E_ 8000
#define ETOT_ 9000

// ws layout (bytes):
//     0: comb   960 f       (T*C combined bias+pos table)
//  3840: P      96 float4   (Wl, Wr, bl+br, 0.4*att)
//  5376: lin    4 f         (0.6*A, 0.6*B, 0.6*Cb)
//  5392: counts 1000 i
//  9392: offs   1001 i      (CSR offsets by dst)
// 13396: srcS   9000 i      (src node per sorted edge slot)
// 49396: dstS   9000 i
// 85396: Lsort  G*9000 f    (logits in sorted-by-dst position)
// 85396+4*G*9000: S  G*N f  (softmax-weighted scalar per node)

__global__ __launch_bounds__(1024) void k1_init(
        const float* __restrict__ Wl, const float* __restrict__ bl,
        const float* __restrict__ Wr, const float* __restrict__ br,
        const float* __restrict__ att, const float* __restrict__ bias,
        float* __restrict__ comb, float4* __restrict__ P,
        float* __restrict__ lin, int* __restrict__ counts) {
    int tid = threadIdx.x;
    if (tid < T_ * C_) {
        int t = tid / C_, c = tid % C_;
        int k = c >> 1;
        float dt = __expf(-(float)(2 * k) * (logf(10000.0f) / (float)C_));
        float ang = (float)t * dt;
        float pe = (c & 1) ? cosf(ang) : sinf(ang);
        comb[tid] = bl[c] + bias[c] + pe;
    }
    if (tid < C_) {
        P[tid] = make_float4(Wl[tid], Wr[tid], bl[tid] + br[tid], 0.4f * att[tid]);
    }
    if (tid == 0) {
        float A = 0.f, B = 0.f, Cb = 0.f;
        for (int c = 0; c < C_; c++) {
            A += att[c] * Wl[c];
            B += att[c] * Wr[c];
            Cb += att[c] * (bl[c] + br[c]);
        }
        lin[0] = 0.6f * A; lin[1] = 0.6f * B; lin[2] = 0.6f * Cb;
    }
    if (tid < N_) counts[tid] = 0;
}

__global__ void k2_count(const int* __restrict__ ei, int* __restrict__ counts) {
    int e = blockIdx.x * blockDim.x + threadIdx.x;
    if (e < ETOT_) {
        int d = (e < E_) ? ei[E_ + e] : (e - E_);
        atomicAdd(&counts[d], 1);
    }
}

__global__ __launch_bounds__(1024) void k3_scan_scatter(
        const int* __restrict__ ei, const int* __restrict__ counts,
        int* __restrict__ offs, int* __restrict__ srcS, int* __restrict__ dstS) {
    __shared__ int sc[1024];
    __shared__ int cur[N_];
    int tid = threadIdx.x;
    int c = (tid < N_) ? counts[tid] : 0;
    sc[tid] = c;
    __syncthreads();
    // Hillis-Steele inclusive scan over 1024
    for (int off = 1; off < 1024; off <<= 1) {
        int v = (tid >= off) ? sc[tid - off] : 0;
        __syncthreads();
        sc[tid] += v;
        __syncthreads();
    }
    if (tid < N_) {
        int excl = sc[tid] - c;
        offs[tid] = excl;
        cur[tid] = excl;
        if (tid == N_ - 1) offs[N_] = sc[tid];
    }
    __syncthreads();
    for (int e = tid; e < ETOT_; e += 1024) {
        int s, d;
        if (e < E_) { s = ei[e]; d = ei[E_ + e]; }
        else        { s = e - E_; d = s; }
        int pos = atomicAdd(&cur[d], 1);
        srcS[pos] = s;
        dstS[pos] = d;
    }
}

// 4 edges per thread; 1024 sorted slots per block; grid (9, G)
__global__ __launch_bounds__(256) void k4_logits(
        const float* __restrict__ x, const float4* __restrict__ P,
        const float* __restrict__ lin, const int* __restrict__ srcS,
        const int* __restrict__ dstS, float* __restrict__ Lsort) {
    __shared__ float4 Ps[C_];
    int tid = threadIdx.x;
    if (tid < C_) Ps[tid] = P[tid];
    float la = lin[0], lb = lin[1], lc = lin[2];
    __syncthreads();
    int g = blockIdx.y;
    const float* xg = x + g * N_;
    int base = blockIdx.x * 1024 + tid;
    float u[4], v[4], acc[4];
    int p[4]; bool ok[4];
#pragma unroll
    for (int k = 0; k < 4; k++) {
        p[k] = base + k * 256;
        ok[k] = p[k] < ETOT_;
        int pp = ok[k] ? p[k] : 0;
        int s = srcS[pp], d = dstS[pp];
        u[k] = xg[s]; v[k] = xg[d];
        acc[k] = 0.f;
    }
#pragma unroll 8
    for (int c = 0; c < C_; c++) {
        float4 q = Ps[c];
#pragma unroll
        for (int k = 0; k < 4; k++) {
            float w = fmaf(u[k], q.x, fmaf(v[k], q.y, q.z));
            acc[k] = fmaf(q.w, fabsf(w), acc[k]);
        }
    }
    float* Lg = Lsort + (size_t)g * ETOT_;
#pragma unroll
    for (int k = 0; k < 4; k++) {
        if (ok[k]) Lg[p[k]] = fmaf(u[k], la, fmaf(v[k], lb, lc)) + acc[k];
    }
}

// one thread per (g,i): branchless online softmax over incoming edges
__global__ __launch_bounds__(256) void k5_softmax(
        const float* __restrict__ x, const float* __restrict__ Lsort,
        const int* __restrict__ offs, const int* __restrict__ srcS,
        float* __restrict__ S) {
    int idx = blockIdx.x * blockDim.x + threadIdx.x;
    if (idx >= G_ * N_) return;
    int g = idx / N_, i = idx - g * N_;
    int start = offs[i], end = offs[i + 1];
    const float* Lg = Lsort + (size_t)g * ETOT_;
    const float* xg = x + g * N_;
    float m = -INFINITY, den = 0.f, num = 0.f;
    for (int p = start; p < end; ++p) {
        float l = Lg[p];
        float uu = xg[srcS[p]];
        float nm = fmaxf(m, l);
        float sc = __expf(m - nm);
        float ex = __expf(l - nm);
        den = den * sc + ex;
        num = fmaf(ex, uu, num * sc);
        m = nm;
    }
    S[idx] = num / den;
}

// coalesced float4 expansion: out[gi,c] = S[gi]*Wl[c] + comb[t,c]
__global__ __launch_bounds__(256) void k6_expand(
        const float* __restrict__ S, const float* __restrict__ Wl,
        const float* __restrict__ comb, float4* __restrict__ out) {
    unsigned idx = blockIdx.x * blockDim.x + threadIdx.x; // exactly G*N*24
    unsigned gi = idx / 24u;
    unsigned c4 = idx - gi * 24u;
    unsigned g = gi / (unsigned)N_;
    unsigned t = g % (unsigned)T_;
    float s = S[gi];
    float4 w = ((const float4*)Wl)[c4];
    float4 cb = ((const float4*)comb)[t * 24u + c4];
    out[idx] = make_float4(fmaf(s, w.x, cb.x), fmaf(s, w.y, cb.y),
                           fmaf(s, w.z, cb.z), fmaf(s, w.w, cb.w));
}

extern "C" void kernel_launch(void* const* d_in, const int* in_sizes, int n_in,
                              void* d_out, int out_size, void* d_ws, size_t ws_size,
                              hipStream_t stream) {
    const float* x    = (const float*)d_in[0];
    const int*   ei   = (const int*)d_in[1];
    const float* Wl   = (const float*)d_in[2];
    const float* bl   = (const float*)d_in[3];
    const float* Wr   = (const float*)d_in[4];
    const float* br   = (const float*)d_in[5];
    const float* att  = (const float*)d_in[6];
    const float* bias = (const float*)d_in[7];
    float4* out = (float4*)d_out;

    char* ws = (char*)d_ws;
    float*  comb   = (float*)(ws + 0);
    float4* P      = (float4*)(ws + 3840);
    float*  lin    = (float*)(ws + 5376);
    int*    counts = (int*)(ws + 5392);
    int*    offs   = (int*)(ws + 9392);
    int*    srcS   = (int*)(ws + 13396);
    int*    dstS   = (int*)(ws + 49396);
    float*  Lsort  = (float*)(ws + 85396);
    float*  S      = (float*)(ws + 85396 + 4 * (size_t)G_ * ETOT_);

    hipLaunchKernelGGL(k1_init, dim3(1), dim3(1024), 0, stream,
                       Wl, bl, Wr, br, att, bias, comb, P, lin, counts);
    hipLaunchKernelGGL(k2_count, dim3((ETOT_ + 255) / 256), dim3(256), 0, stream,
                       ei, counts);
    hipLaunchKernelGGL(k3_scan_scatter, dim3(1), dim3(1024), 0, stream,
                       ei, counts, offs, srcS, dstS);
    hipLaunchKernelGGL(k4_logits, dim3(9, G_), dim3(256), 0, stream,
                       x, P, lin, srcS, dstS, Lsort);
    hipLaunchKernelGGL(k5_softmax, dim3((G_ * N_ + 255) / 256), dim3(256), 0, stream,
                       x, Lsort, offs, srcS, S);
    hipLaunchKernelGGL(k6_expand, dim3(30000), dim3(256), 0, stream,
                       S, Wl, comb, out);
}

// Round 3
// 79.993 us; speedup vs baseline: 1.1425x; 1.1425x over previous
//
#include <hip/hip_runtime.h>
#include <math.h>

#define G_ 320
#define N_ 1000
#define T_ 10
#define C_ 96
#define E_ 8000
#define ETOT_ 9000
#define HALF_N 500
#define LMAX 5120

// ws layout (bytes):
//     0: comb  960 f   (T*C combined bl+bias+pos table)
//  3840: P     96 f4   (Wl, Wr, bl+br, 0.4*att)
//  5376: lin   4 f     (0.6*A, 0.6*B, 0.6*Cb)
//  5392: offs  1001 i  (CSR offsets by dst)
//  9400: srcS  9000 i
// 45400: dstS  9000 i
// 81400: S     G*N f   (softmax-weighted scalar per node)

// ---------- kA: setup + count + scan + scatter (one block) ----------
__global__ __launch_bounds__(1024) void kA(
        const int* __restrict__ ei,
        const float* __restrict__ Wl, const float* __restrict__ bl,
        const float* __restrict__ Wr, const float* __restrict__ br,
        const float* __restrict__ att, const float* __restrict__ bias,
        float* __restrict__ comb, float4* __restrict__ P,
        float* __restrict__ lin, int* __restrict__ offs,
        int* __restrict__ srcS, int* __restrict__ dstS) {
    __shared__ int cnt[1024];
    __shared__ int cur[N_];
    __shared__ float pA[C_], pB[C_], pC[C_];
    int tid = threadIdx.x;

    // combined bias table
    if (tid < T_ * C_) {
        int t = tid / C_, c = tid % C_;
        int k = c >> 1;
        float dt = __expf(-(float)(2 * k) * (logf(10000.0f) / (float)C_));
        float ang = (float)t * dt;
        float pe = (c & 1) ? cosf(ang) : sinf(ang);
        comb[tid] = bl[c] + bias[c] + pe;
    }
    // packed channel params + lin products
    if (tid < C_) {
        float wl = Wl[tid], wr = Wr[tid], bb = bl[tid] + br[tid], a = att[tid];
        P[tid] = make_float4(wl, wr, bb, 0.4f * a);
        pA[tid] = a * wl; pB[tid] = a * wr; pC[tid] = a * bb;
    }
    cnt[tid] = 0;
    __syncthreads();
    if (tid == 0) {
        float A = 0.f, B = 0.f, Cb = 0.f;
        for (int c = 0; c < C_; c++) { A += pA[c]; B += pB[c]; Cb += pC[c]; }
        lin[0] = 0.6f * A; lin[1] = 0.6f * B; lin[2] = 0.6f * Cb;
    }
    // count (LDS atomics)
    for (int e = tid; e < ETOT_; e += 1024) {
        int d = (e < E_) ? ei[E_ + e] : (e - E_);
        atomicAdd(&cnt[d], 1);
    }
    __syncthreads();
    int c = cnt[tid];
    // Hillis-Steele inclusive scan over 1024
    for (int off = 1; off < 1024; off <<= 1) {
        int v = (tid >= off) ? cnt[tid - off] : 0;
        __syncthreads();
        cnt[tid] += v;
        __syncthreads();
    }
    if (tid < N_) {
        int excl = cnt[tid] - c;
        offs[tid] = excl;
        cur[tid] = excl;
    }
    if (tid == 0) offs[N_] = ETOT_;
    __syncthreads();
    // scatter (counting sort by dst)
    for (int e = tid; e < ETOT_; e += 1024) {
        int s, d;
        if (e < E_) { s = ei[e]; d = ei[E_ + e]; }
        else        { s = e - E_; d = s; }
        int pos = atomicAdd(&cur[d], 1);
        srcS[pos] = s;
        dstS[pos] = d;
    }
}

// ---------- kB: logits + per-node softmax, per (graph, node-half) ----------
// grid (2, G_), 512 threads. Node range [h*500,(h+1)*500) -> contiguous
// sorted-slot range [offs[h*500], offs[h*500+500]) ; logits stay in LDS.
__global__ __launch_bounds__(512) void kB(
        const float* __restrict__ x, const float4* __restrict__ P,
        const float* __restrict__ lin, const int* __restrict__ offs,
        const int* __restrict__ srcS, const int* __restrict__ dstS,
        float* __restrict__ S) {
    __shared__ float xgs[N_];
    __shared__ float4 Ps[C_];
    __shared__ float L[LMAX];
    __shared__ int offsL[HALF_N + 1];
    int tid = threadIdx.x;
    int h = blockIdx.x, g = blockIdx.y;
    const float* xg = x + g * N_;
    for (int i = tid; i < N_; i += 512) xgs[i] = xg[i];
    if (tid < C_) Ps[tid] = P[tid];
    int nbase = h * HALF_N;
    for (int i = tid; i <= HALF_N; i += 512) offsL[i] = offs[nbase + i];
    float la = lin[0], lb = lin[1], lc = lin[2];
    __syncthreads();
    int s0 = offsL[0];
    int cnt = offsL[HALF_N] - s0;

    // logit phase: 3 slots per thread per pass
    for (int base = tid; base < cnt; base += 512 * 3) {
        int p[3]; bool ok[3]; float u[3], v[3], acc[3];
#pragma unroll
        for (int k = 0; k < 3; k++) {
            p[k] = base + k * 512;
            ok[k] = p[k] < cnt;
            int pp = s0 + (ok[k] ? p[k] : 0);
            int s = srcS[pp], d = dstS[pp];
            u[k] = xgs[s]; v[k] = xgs[d]; acc[k] = 0.f;
        }
#pragma unroll 8
        for (int c = 0; c < C_; c++) {
            float4 q = Ps[c];
#pragma unroll
            for (int k = 0; k < 3; k++) {
                float w = fmaf(u[k], q.x, fmaf(v[k], q.y, q.z));
                acc[k] = fmaf(q.w, fabsf(w), acc[k]);
            }
        }
#pragma unroll
        for (int k = 0; k < 3; k++)
            if (ok[k]) L[p[k]] = fmaf(u[k], la, fmaf(v[k], lb, lc)) + acc[k];
    }
    __syncthreads();

    // per-node branchless online softmax -> scalar S
    if (tid < HALF_N) {
        int a = offsL[tid] - s0, b = offsL[tid + 1] - s0;
        float m = -INFINITY, den = 0.f, num = 0.f;
        for (int q = a; q < b; ++q) {
            float l = L[q];
            float uu = xgs[srcS[s0 + q]];
            float nm = fmaxf(m, l);
            float sc = __expf(m - nm);
            float ex = __expf(l - nm);
            den = den * sc + ex;
            num = fmaf(ex, uu, num * sc);
            m = nm;
        }
        S[g * N_ + nbase + tid] = num / den;
    }
}

// ---------- kC: coalesced float4 expansion ----------
__global__ __launch_bounds__(256) void kC(
        const float* __restrict__ S, const float* __restrict__ Wl,
        const float* __restrict__ comb, float4* __restrict__ out) {
    unsigned idx = blockIdx.x * blockDim.x + threadIdx.x; // exactly G*N*24
    unsigned gi = idx / 24u;
    unsigned c4 = idx - gi * 24u;
    unsigned g = gi / (unsigned)N_;
    unsigned t = g % (unsigned)T_;
    float s = S[gi];
    float4 w = ((const float4*)Wl)[c4];
    float4 cb = ((const float4*)comb)[t * 24u + c4];
    out[idx] = make_float4(fmaf(s, w.x, cb.x), fmaf(s, w.y, cb.y),
                           fmaf(s, w.z, cb.z), fmaf(s, w.w, cb.w));
}

extern "C" void kernel_launch(void* const* d_in, const int* in_sizes, int n_in,
                              void* d_out, int out_size, void* d_ws, size_t ws_size,
                              hipStream_t stream) {
    const float* x    = (const float*)d_in[0];
    const int*   ei   = (const int*)d_in[1];
    const float* Wl   = (const float*)d_in[2];
    const float* bl   = (const float*)d_in[3];
    const float* Wr   = (const float*)d_in[4];
    const float* br   = (const float*)d_in[5];
    const float* att  = (const float*)d_in[6];
    const float* bias = (const float*)d_in[7];
    float4* out = (float4*)d_out;

    char* ws = (char*)d_ws;
    float*  comb = (float*)(ws + 0);
    float4* P    = (float4*)(ws + 3840);
    float*  lin  = (float*)(ws + 5376);
    int*    offs = (int*)(ws + 5392);
    int*    srcS = (int*)(ws + 9400);
    int*    dstS = (int*)(ws + 45400);
    float*  S    = (float*)(ws + 81400);

    hipLaunchKernelGGL(kA, dim3(1), dim3(1024), 0, stream,
                       ei, Wl, bl, Wr, br, att, bias, comb, P, lin, offs, srcS, dstS);
    hipLaunchKernelGGL(kB, dim3(2, G_), dim3(512), 0, stream,
                       x, P, lin, offs, srcS, dstS, S);
    hipLaunchKernelGGL(kC, dim3(30000), dim3(256), 0, stream,
                       S, Wl, comb, out);
}

// Round 4
// 74.102 us; speedup vs baseline: 1.2334x; 1.0795x over previous
//
#include <hip/hip_runtime.h>
#include <math.h>

#define G_ 320
#define N_ 1000
#define T_ 10
#define C_ 96
#define E_ 8000
#define ETOT_ 9000
#define HALF_N 500
#define LMAX 5504

// ws layout (bytes):
//     0: comb  960 f   (T*C combined bl+bias+pos table)
//  3840: P     96 f4   (Wl, Wr, bl+br, 0.4*att)
//  5376: lin   4 f     (0.6*A, 0.6*B, 0.6*Cb)
//  5392: offs  1001 i  (CSR offsets by dst)
//  9400: srcS  9000 i
// 45400: dstS  9000 i

// ---------- kA: setup + count + scan + scatter (one block) ----------
__global__ __launch_bounds__(1024) void kA(
        const int* __restrict__ ei,
        const float* __restrict__ Wl, const float* __restrict__ bl,
        const float* __restrict__ Wr, const float* __restrict__ br,
        const float* __restrict__ att, const float* __restrict__ bias,
        float* __restrict__ comb, float4* __restrict__ P,
        float* __restrict__ lin, int* __restrict__ offs,
        int* __restrict__ srcS, int* __restrict__ dstS) {
    __shared__ int cnt[1024];
    __shared__ int cur[N_];
    __shared__ float pA[C_], pB[C_], pC[C_];
    int tid = threadIdx.x;

    // combined bias table
    if (tid < T_ * C_) {
        int t = tid / C_, c = tid % C_;
        int k = c >> 1;
        float dt = __expf(-(float)(2 * k) * (logf(10000.0f) / (float)C_));
        float ang = (float)t * dt;
        float pe = (c & 1) ? cosf(ang) : sinf(ang);
        comb[tid] = bl[c] + bias[c] + pe;
    }
    // packed channel params + lin products
    if (tid < C_) {
        float wl = Wl[tid], wr = Wr[tid], bb = bl[tid] + br[tid], a = att[tid];
        P[tid] = make_float4(wl, wr, bb, 0.4f * a);
        pA[tid] = a * wl; pB[tid] = a * wr; pC[tid] = a * bb;
    }
    cnt[tid] = 0;
    __syncthreads();
    if (tid == 0) {
        float A = 0.f, B = 0.f, Cb = 0.f;
        for (int c = 0; c < C_; c++) { A += pA[c]; B += pB[c]; Cb += pC[c]; }
        lin[0] = 0.6f * A; lin[1] = 0.6f * B; lin[2] = 0.6f * Cb;
    }
    // count (LDS atomics)
    for (int e = tid; e < ETOT_; e += 1024) {
        int d = (e < E_) ? ei[E_ + e] : (e - E_);
        atomicAdd(&cnt[d], 1);
    }
    __syncthreads();
    int c = cnt[tid];
    // Hillis-Steele inclusive scan over 1024
    for (int off = 1; off < 1024; off <<= 1) {
        int v = (tid >= off) ? cnt[tid - off] : 0;
        __syncthreads();
        cnt[tid] += v;
        __syncthreads();
    }
    if (tid < N_) {
        int excl = cnt[tid] - c;
        offs[tid] = excl;
        cur[tid] = excl;
    }
    if (tid == 0) offs[N_] = ETOT_;
    __syncthreads();
    // scatter (counting sort by dst)
    for (int e = tid; e < ETOT_; e += 1024) {
        int s, d;
        if (e < E_) { s = ei[e]; d = ei[E_ + e]; }
        else        { s = e - E_; d = s; }
        int pos = atomicAdd(&cur[d], 1);
        srcS[pos] = s;
        dstS[pos] = d;
    }
}

// ---------- kB: logits + softmax + fused output expansion ----------
// grid (2, G_), 512 threads. Node range [h*500,(h+1)*500) owns contiguous
// sorted-slot range; logits + S stay in LDS; output slab written directly.
__global__ __launch_bounds__(512) void kB(
        const float* __restrict__ x, const float4* __restrict__ P,
        const float* __restrict__ lin, const int* __restrict__ offs,
        const int* __restrict__ srcS, const int* __restrict__ dstS,
        const float* __restrict__ comb, float4* __restrict__ out) {
    __shared__ float xgs[N_];
    __shared__ float4 Ps[C_];
    __shared__ float L[LMAX];
    __shared__ int offsL[HALF_N + 1];
    __shared__ float Sloc[HALF_N];
    __shared__ float4 cb4[C_ / 4];
    __shared__ float4 wl4[C_ / 4];
    int tid = threadIdx.x;
    int h = blockIdx.x, g = blockIdx.y;
    int t = g % T_;
    const float* xg = x + g * N_;
    for (int i = tid; i < N_; i += 512) xgs[i] = xg[i];
    if (tid < C_) Ps[tid] = P[tid];
    int nbase = h * HALF_N;
    for (int i = tid; i <= HALF_N; i += 512) offsL[i] = offs[nbase + i];
    if (tid < C_ / 4) cb4[tid] = ((const float4*)(comb + t * C_))[tid];
    float la = lin[0], lb = lin[1], lc = lin[2];
    __syncthreads();
    if (tid < C_ / 4)
        wl4[tid] = make_float4(Ps[4 * tid].x, Ps[4 * tid + 1].x,
                               Ps[4 * tid + 2].x, Ps[4 * tid + 3].x);
    int s0 = offsL[0];
    int cnt = offsL[HALF_N] - s0;

    // logit phase: 3 slots per thread per pass
    for (int base = tid; base < cnt; base += 512 * 3) {
        int p[3]; bool ok[3]; float u[3], v[3], acc[3];
#pragma unroll
        for (int k = 0; k < 3; k++) {
            p[k] = base + k * 512;
            ok[k] = p[k] < cnt;
            int pp = s0 + (ok[k] ? p[k] : 0);
            int s = srcS[pp], d = dstS[pp];
            u[k] = xgs[s]; v[k] = xgs[d]; acc[k] = 0.f;
        }
#pragma unroll 8
        for (int c = 0; c < C_; c++) {
            float4 q = Ps[c];
#pragma unroll
            for (int k = 0; k < 3; k++) {
                float w = fmaf(u[k], q.x, fmaf(v[k], q.y, q.z));
                acc[k] = fmaf(q.w, fabsf(w), acc[k]);
            }
        }
#pragma unroll
        for (int k = 0; k < 3; k++)
            if (ok[k]) L[p[k]] = fmaf(u[k], la, fmaf(v[k], lb, lc)) + acc[k];
    }
    __syncthreads();

    // per-node branchless online softmax -> Sloc
    if (tid < HALF_N) {
        int a = offsL[tid] - s0, b = offsL[tid + 1] - s0;
        float m = -INFINITY, den = 0.f, num = 0.f;
        for (int q = a; q < b; ++q) {
            float l = L[q];
            float uu = xgs[srcS[s0 + q]];
            float nm = fmaxf(m, l);
            float sc = __expf(m - nm);
            float ex = __expf(l - nm);
            den = den * sc + ex;
            num = fmaf(ex, uu, num * sc);
            m = nm;
        }
        Sloc[tid] = num / den;
    }
    __syncthreads();

    // fused expansion: contiguous 500x96-float slab, float4 coalesced
    float4* out4 = out + (size_t)(g * N_ + nbase) * (C_ / 4);
    for (int i = tid; i < HALF_N * (C_ / 4); i += 512) {
        int node = i / (C_ / 4);
        int c4 = i - node * (C_ / 4);
        float s = Sloc[node];
        float4 w = wl4[c4], cb = cb4[c4];
        out4[i] = make_float4(fmaf(s, w.x, cb.x), fmaf(s, w.y, cb.y),
                              fmaf(s, w.z, cb.z), fmaf(s, w.w, cb.w));
    }
}

extern "C" void kernel_launch(void* const* d_in, const int* in_sizes, int n_in,
                              void* d_out, int out_size, void* d_ws, size_t ws_size,
                              hipStream_t stream) {
    const float* x    = (const float*)d_in[0];
    const int*   ei   = (const int*)d_in[1];
    const float* Wl   = (const float*)d_in[2];
    const float* bl   = (const float*)d_in[3];
    const float* Wr   = (const float*)d_in[4];
    const float* br   = (const float*)d_in[5];
    const float* att  = (const float*)d_in[6];
    const float* bias = (const float*)d_in[7];
    float4* out = (float4*)d_out;

    char* ws = (char*)d_ws;
    float*  comb = (float*)(ws + 0);
    float4* P    = (float4*)(ws + 3840);
    float*  lin  = (float*)(ws + 5376);
    int*    offs = (int*)(ws + 5392);
    int*    srcS = (int*)(ws + 9400);
    int*    dstS = (int*)(ws + 45400);

    hipLaunchKernelGGL(kA, dim3(1), dim3(1024), 0, stream,
                       ei, Wl, bl, Wr, br, att, bias, comb, P, lin, offs, srcS, dstS);
    hipLaunchKernelGGL(kB, dim3(2, G_), dim3(512), 0, stream,
                       x, P, lin, offs, srcS, dstS, comb, out);
}

// Round 5
// 74.035 us; speedup vs baseline: 1.2345x; 1.0009x over previous
//
#include <hip/hip_runtime.h>
#include <math.h>

#define G_ 320
#define N_ 1000
#define T_ 10
#define C_ 96
#define E_ 8000
#define QN 250          // nodes per block (4 blocks per graph)
#define CAP 2816        // edge-slot capacity per block (mean ~2250, sigma ~39)
#define EPT 5           // edge slots per thread in main logit pass

// Single fused kernel: per-block local CSR build + logits + softmax + expand.
// out[g,n,c] = S[g,n]*Wl[c] + (bl[c]+bias[c]+pos[t,c]),
// S[g,n] = softmax-weighted mean of x[g,src] over incoming edges of n.
__global__ __launch_bounds__(512, 4) void fused(
        const float* __restrict__ x, const int* __restrict__ ei,
        const float* __restrict__ Wl, const float* __restrict__ bl,
        const float* __restrict__ Wr, const float* __restrict__ br,
        const float* __restrict__ att, const float* __restrict__ bias,
        float4* __restrict__ out) {
    __shared__ float  xgs[N_];
    __shared__ float4 Ps[C_];          // (wl, wr, bl+br, 0.4*att)
    __shared__ float2 uv[CAP];         // (u,v)  ->  (logit,u) in place
    __shared__ int    cnt[256];        // per-node in-degree (padded)
    __shared__ int    offsL[260];      // exclusive offsets (scan writes in 4s)
    __shared__ int    cur[256];
    __shared__ float  Sloc[QN];
    __shared__ float4 wl4[C_ / 4], cb4[C_ / 4];
    __shared__ float  lin3[3];

    const int tid = threadIdx.x;
    const int h = blockIdx.x;          // quarter 0..3
    const int g = blockIdx.y;          // graph 0..319
    const int lo = h * QN;
    const int t = g % T_;

    const float* xg = x + g * N_;
    for (int i = tid; i < N_; i += 512) xgs[i] = xg[i];
    for (int i = tid; i < 256; i += 512) cnt[i] = (i < QN) ? 1 : 0; // self-loop
    if (tid < C_) {
        float wlv = Wl[tid], wrv = Wr[tid], blv = bl[tid];
        float bb = blv + br[tid], a = att[tid];
        Ps[tid] = make_float4(wlv, wrv, bb, 0.4f * a);
        int k2 = tid & ~1;
        float dt = __expf(-(float)k2 * (logf(10000.0f) / (float)C_));
        float ang = (float)t * dt;
        float pe = (tid & 1) ? cosf(ang) : sinf(ang);
        ((float*)wl4)[tid] = wlv;
        ((float*)cb4)[tid] = blv + bias[tid] + pe;
    }
    {   // lin3 = 0.6 * { sum a*Wl, sum a*Wr, sum a*(bl+br) } (3 parallel waves)
        int w = tid >> 6, lane = tid & 63;
        if (w < 3) {
            float s = 0.f;
            for (int i = lane; i < C_; i += 64) {
                float a = att[i];
                float m = (w == 0) ? Wl[i] : (w == 1) ? Wr[i] : (bl[i] + br[i]);
                s += a * m;
            }
            for (int off = 32; off; off >>= 1) s += __shfl_down(s, off);
            if (lane == 0) lin3[w] = 0.6f * s;
        }
    }
    __syncthreads();

    // count in-range real edges
    for (int e = tid; e < E_; e += 512) {
        int r = ei[E_ + e] - lo;
        if ((unsigned)r < (unsigned)QN) atomicAdd(&cnt[r], 1);
    }
    __syncthreads();

    // wave-0 shuffle scan over 256 padded counters (lane owns 4)
    if (tid < 64) {
        int b4 = tid * 4;
        int a0 = cnt[b4], a1 = cnt[b4 + 1], a2 = cnt[b4 + 2], a3 = cnt[b4 + 3];
        int s1 = a0 + a1, s2 = s1 + a2, s3 = s2 + a3;
        int pre = s3;
        for (int off = 1; off < 64; off <<= 1) {
            int tv = __shfl_up(pre, off);
            if (tid >= off) pre += tv;
        }
        int base = pre - s3;  // exclusive prefix
        offsL[b4] = base;         cur[b4] = base;
        offsL[b4 + 1] = base + a0; cur[b4 + 1] = base + a0;
        offsL[b4 + 2] = base + s1; cur[b4 + 2] = base + s1;
        offsL[b4 + 3] = base + s2; cur[b4 + 3] = base + s2;
    }
    __syncthreads();
    const int cntE = offsL[QN];

    // scatter: resolve (u,v) immediately into LDS
    for (int e = tid; e < E_; e += 512) {
        int dd = ei[E_ + e];
        int r = dd - lo;
        if ((unsigned)r < (unsigned)QN) {
            int s = ei[e];
            int pos = atomicAdd(&cur[r], 1);
            uv[pos] = make_float2(xgs[s], xgs[dd]);
        }
    }
    for (int i = tid; i < QN; i += 512) {       // self-loops
        int pos = atomicAdd(&cur[i], 1);
        float xv = xgs[lo + i];
        uv[pos] = make_float2(xv, xv);
    }
    __syncthreads();

    // logit phase: e = 0.6*(u*A+v*B+Cb) + sum_c 0.4*att_c*|u*wl_c+v*wr_c+bb_c|
    const float la = lin3[0], lb = lin3[1], lc = lin3[2];
    {
        float u[EPT], v[EPT], acc[EPT];
#pragma unroll
        for (int k = 0; k < EPT; k++) {
            int p = tid + k * 512;
            float2 e2 = uv[p < cntE ? p : 0];
            u[k] = e2.x; v[k] = e2.y; acc[k] = 0.f;
        }
#pragma unroll 4
        for (int c = 0; c < C_; c++) {
            float4 q = Ps[c];
#pragma unroll
            for (int k = 0; k < EPT; k++) {
                float wv = fmaf(u[k], q.x, fmaf(v[k], q.y, q.z));
                acc[k] = fmaf(q.w, fabsf(wv), acc[k]);
            }
        }
#pragma unroll
        for (int k = 0; k < EPT; k++) {
            int p = tid + k * 512;
            if (p < cntE)
                uv[p] = make_float2(fmaf(u[k], la, fmaf(v[k], lb, lc)) + acc[k], u[k]);
        }
    }
    for (int p = tid + 512 * EPT; p < cntE; p += 512) {  // rare overflow slots
        float2 e2 = uv[p];
        float uu = e2.x, vv = e2.y, a2 = 0.f;
        for (int c = 0; c < C_; c++) {
            float4 q = Ps[c];
            float wv = fmaf(uu, q.x, fmaf(vv, q.y, q.z));
            a2 = fmaf(q.w, fabsf(wv), a2);
        }
        uv[p] = make_float2(fmaf(uu, la, fmaf(vv, lb, lc)) + a2, uu);
    }
    __syncthreads();

    // per-node branchless online softmax -> scalar S
    if (tid < QN) {
        int a = offsL[tid], b = offsL[tid + 1];
        float m = -INFINITY, den = 0.f, num = 0.f;
        for (int q = a; q < b; ++q) {
            float2 lu = uv[q];
            float nm = fmaxf(m, lu.x);
            float sc = __expf(m - nm);
            float ex = __expf(lu.x - nm);
            den = den * sc + ex;
            num = fmaf(ex, lu.y, num * sc);
            m = nm;
        }
        Sloc[tid] = num / den;
    }
    __syncthreads();

    // expansion: contiguous 250x96-float slab, float4 coalesced
    float4* out4 = out + (size_t)(g * N_ + lo) * (C_ / 4);
    for (int i = tid; i < QN * (C_ / 4); i += 512) {
        int node = i / (C_ / 4);
        int c4 = i - node * (C_ / 4);
        float s = Sloc[node];
        float4 wv = wl4[c4], cb = cb4[c4];
        out4[i] = make_float4(fmaf(s, wv.x, cb.x), fmaf(s, wv.y, cb.y),
                              fmaf(s, wv.z, cb.z), fmaf(s, wv.w, cb.w));
    }
}

extern "C" void kernel_launch(void* const* d_in, const int* in_sizes, int n_in,
                              void* d_out, int out_size, void* d_ws, size_t ws_size,
                              hipStream_t stream) {
    const float* x    = (const float*)d_in[0];
    const int*   ei   = (const int*)d_in[1];
    const float* Wl   = (const float*)d_in[2];
    const float* bl   = (const float*)d_in[3];
    const float* Wr   = (const float*)d_in[4];
    const float* br   = (const float*)d_in[5];
    const float* att  = (const float*)d_in[6];
    const float* bias = (const float*)d_in[7];
    float4* out = (float4*)d_out;

    hipLaunchKernelGGL(fused, dim3(4, G_), dim3(512), 0, stream,
                       x, ei, Wl, bl, Wr, br, att, bias, out);
}

// Round 6
// 70.287 us; speedup vs baseline: 1.3003x; 1.0533x over previous
//
#include <hip/hip_runtime.h>
#include <math.h>

#define G_ 320
#define N_ 1000
#define T_ 10
#define C_ 96
#define E_ 8000
#define QN 250          // nodes per block (4 blocks per graph)
#define CAP 2816        // edge-slot capacity per block (mean ~2250)
#define EPT 5           // edge slots per thread in main logit pass

#define TOT4 (G_ * N_ * (C_ / 4))      // 7,680,000 float4s of output
#define KE_BLOCKS 2016                 // stride 516096 divisible by 24
#define KE_STRIDE (KE_BLOCKS * 256)

// ---------------- kS: CSR build + logits + softmax -> S[g,n] ----------------
__global__ __launch_bounds__(512, 4) void kS(
        const float* __restrict__ x, const int* __restrict__ ei,
        const float* __restrict__ Wl, const float* __restrict__ bl,
        const float* __restrict__ Wr, const float* __restrict__ br,
        const float* __restrict__ att, float* __restrict__ S) {
    __shared__ float  xgs[N_];
    __shared__ float4 Ps[C_];          // (wl, wr, bl+br, 0.4*att)
    __shared__ float2 uv[CAP];         // (u,v) -> (logit,u) in place
    __shared__ int    cnt[256];
    __shared__ int    offsL[260];
    __shared__ int    cur[256];
    __shared__ float  lin3[3];

    const int tid = threadIdx.x;
    const int h = blockIdx.x;
    const int g = blockIdx.y;
    const int lo = h * QN;

    const float* xg = x + g * N_;
    if (tid < N_ / 4) ((float4*)xgs)[tid] = ((const float4*)xg)[tid];
    for (int i = tid; i < 256; i += 512) cnt[i] = (i < QN) ? 1 : 0; // self-loop
    if (tid < C_) {
        float wlv = Wl[tid], wrv = Wr[tid];
        float bb = bl[tid] + br[tid], a = att[tid];
        Ps[tid] = make_float4(wlv, wrv, bb, 0.4f * a);
    }
    {   // lin3 = 0.6 * { sum a*Wl, sum a*Wr, sum a*(bl+br) }
        int w = tid >> 6, lane = tid & 63;
        if (w < 3) {
            float s = 0.f;
            for (int i = lane; i < C_; i += 64) {
                float a = att[i];
                float m = (w == 0) ? Wl[i] : (w == 1) ? Wr[i] : (bl[i] + br[i]);
                s += a * m;
            }
            for (int off = 32; off; off >>= 1) s += __shfl_down(s, off);
            if (lane == 0) lin3[w] = 0.6f * s;
        }
    }
    __syncthreads();

    // count in-range real edges (int4 loads: 4 edges per 16B)
    const int4* d4 = (const int4*)(ei + E_);
    const int4* s4 = (const int4*)ei;
    for (int j = tid; j < E_ / 4; j += 512) {
        int4 d = d4[j];
        int r0 = d.x - lo, r1 = d.y - lo, r2 = d.z - lo, r3 = d.w - lo;
        if ((unsigned)r0 < (unsigned)QN) atomicAdd(&cnt[r0], 1);
        if ((unsigned)r1 < (unsigned)QN) atomicAdd(&cnt[r1], 1);
        if ((unsigned)r2 < (unsigned)QN) atomicAdd(&cnt[r2], 1);
        if ((unsigned)r3 < (unsigned)QN) atomicAdd(&cnt[r3], 1);
    }
    __syncthreads();

    // wave-0 shuffle scan over 256 padded counters (lane owns 4)
    if (tid < 64) {
        int b4 = tid * 4;
        int a0 = cnt[b4], a1 = cnt[b4 + 1], a2 = cnt[b4 + 2], a3 = cnt[b4 + 3];
        int s1 = a0 + a1, s2 = s1 + a2, s3 = s2 + a3;
        int pre = s3;
        for (int off = 1; off < 64; off <<= 1) {
            int tv = __shfl_up(pre, off);
            if (tid >= off) pre += tv;
        }
        int base = pre - s3;
        offsL[b4] = base;          cur[b4] = base;
        offsL[b4 + 1] = base + a0; cur[b4 + 1] = base + a0;
        offsL[b4 + 2] = base + s1; cur[b4 + 2] = base + s1;
        offsL[b4 + 3] = base + s2; cur[b4 + 3] = base + s2;
    }
    __syncthreads();
    const int cntE = offsL[QN];

    // scatter: resolve (u,v) immediately into LDS (int4 loads)
    for (int j = tid; j < E_ / 4; j += 512) {
        int4 d = d4[j];
        int4 s = s4[j];
#define SCAT(DD, SS) { int r = (DD) - lo;                                   \
        if ((unsigned)r < (unsigned)QN) {                                    \
            int pos = atomicAdd(&cur[r], 1);                                 \
            uv[pos] = make_float2(xgs[SS], xgs[DD]); } }
        SCAT(d.x, s.x) SCAT(d.y, s.y) SCAT(d.z, s.z) SCAT(d.w, s.w)
#undef SCAT
    }
    for (int i = tid; i < QN; i += 512) {       // self-loops
        int pos = atomicAdd(&cur[i], 1);
        float xv = xgs[lo + i];
        uv[pos] = make_float2(xv, xv);
    }
    __syncthreads();

    // logits: e = 0.6*(u*A+v*B+Cb) + sum_c 0.4*att_c*|u*wl_c+v*wr_c+bb_c|
    const float la = lin3[0], lb = lin3[1], lc = lin3[2];
    {
        float u[EPT], v[EPT], acc[EPT];
#pragma unroll
        for (int k = 0; k < EPT; k++) {
            int p = tid + k * 512;
            float2 e2 = uv[p < cntE ? p : 0];
            u[k] = e2.x; v[k] = e2.y; acc[k] = 0.f;
        }
#pragma unroll 4
        for (int c = 0; c < C_; c++) {
            float4 q = Ps[c];
#pragma unroll
            for (int k = 0; k < EPT; k++) {
                float wv = fmaf(u[k], q.x, fmaf(v[k], q.y, q.z));
                acc[k] = fmaf(q.w, fabsf(wv), acc[k]);
            }
        }
#pragma unroll
        for (int k = 0; k < EPT; k++) {
            int p = tid + k * 512;
            if (p < cntE)
                uv[p] = make_float2(fmaf(u[k], la, fmaf(v[k], lb, lc)) + acc[k], u[k]);
        }
    }
    for (int p = tid + 512 * EPT; p < cntE; p += 512) {  // rare overflow
        float2 e2 = uv[p];
        float uu = e2.x, vv = e2.y, a2 = 0.f;
        for (int c = 0; c < C_; c++) {
            float4 q = Ps[c];
            float wv = fmaf(uu, q.x, fmaf(vv, q.y, q.z));
            a2 = fmaf(q.w, fabsf(wv), a2);
        }
        uv[p] = make_float2(fmaf(uu, la, fmaf(vv, lb, lc)) + a2, uu);
    }
    __syncthreads();

    // per-node branchless online softmax -> scalar S (global, 1.28 MB total)
    if (tid < QN) {
        int a = offsL[tid], b = offsL[tid + 1];
        float m = -INFINITY, den = 0.f, num = 0.f;
        for (int q = a; q < b; ++q) {
            float2 lu = uv[q];
            float nm = fmaxf(m, lu.x);
            float sc = __expf(m - nm);
            float ex = __expf(lu.x - nm);
            den = den * sc + ex;
            num = fmaf(ex, lu.y, num * sc);
            m = nm;
        }
        S[g * N_ + lo + tid] = num / den;
    }
}

// ---------------- kE: pure streaming expansion ----------------
// out[gi,c] = S[gi]*Wl[c] + (bl[c]+bias[c]+pos[t,c]); t = (gi/N)%T
__global__ __launch_bounds__(256) void kE(
        const float* __restrict__ S, const float* __restrict__ Wl,
        const float* __restrict__ bl, const float* __restrict__ bias,
        float4* __restrict__ out) {
    __shared__ float4 cbT[T_][C_ / 4];
    const int tid = threadIdx.x;
    if (tid < T_ * (C_ / 4)) {
        int t = tid / (C_ / 4), c4i = tid % (C_ / 4);
        float4 v;
        float* vp = (float*)&v;
#pragma unroll
        for (int j = 0; j < 4; j++) {
            int c = c4i * 4 + j;
            int k2 = c & ~1;
            float dt = __expf(-(float)k2 * (logf(10000.0f) / (float)C_));
            float ang = (float)t * dt;
            float pe = (c & 1) ? cosf(ang) : sinf(ang);
            vp[j] = bl[c] + bias[c] + pe;
        }
        cbT[t][c4i] = v;
    }
    unsigned idx0 = blockIdx.x * 256u + tid;
    int c4 = idx0 % 24u;                       // constant per thread
    float4 wl = ((const float4*)Wl)[c4];       // registers, loaded once
    __syncthreads();
    for (unsigned idx = idx0; idx < (unsigned)TOT4; idx += KE_STRIDE) {
        unsigned gi = idx / 24u;
        unsigned t = (gi / (unsigned)N_) % (unsigned)T_;
        float s = S[gi];
        float4 cb = cbT[t][c4];
        out[idx] = make_float4(fmaf(s, wl.x, cb.x), fmaf(s, wl.y, cb.y),
                               fmaf(s, wl.z, cb.z), fmaf(s, wl.w, cb.w));
    }
}

extern "C" void kernel_launch(void* const* d_in, const int* in_sizes, int n_in,
                              void* d_out, int out_size, void* d_ws, size_t ws_size,
                              hipStream_t stream) {
    const float* x    = (const float*)d_in[0];
    const int*   ei   = (const int*)d_in[1];
    const float* Wl   = (const float*)d_in[2];
    const float* bl   = (const float*)d_in[3];
    const float* Wr   = (const float*)d_in[4];
    const float* br   = (const float*)d_in[5];
    const float* att  = (const float*)d_in[6];
    const float* bias = (const float*)d_in[7];
    float4* out = (float4*)d_out;
    float* S = (float*)d_ws;                   // G*N floats = 1.28 MB

    hipLaunchKernelGGL(kS, dim3(4, G_), dim3(512), 0, stream,
                       x, ei, Wl, bl, Wr, br, att, S);
    hipLaunchKernelGGL(kE, dim3(KE_BLOCKS), dim3(256), 0, stream,
                       S, Wl, bl, bias, out);
}

// Round 7
// 66.745 us; speedup vs baseline: 1.3693x; 1.0531x over previous
//
#include <hip/hip_runtime.h>
#include <math.h>

#define G_ 320
#define N_ 1000
#define T_ 10
#define C_ 96
#define E_ 8000
#define QN 250          // nodes per quarter (4 quarters)
#define CAP 2816        // slot capacity per quarter (mean ~2250, >14 sigma)
#define EPT 5           // slots per thread in main logit pass

#define TOT4 (G_ * N_ * (C_ / 4))      // 7,680,000 float4s of output
#define KE_BLOCKS 2016                 // stride 516096 divisible by 24
#define KE_STRIDE (KE_BLOCKS * 256)

// ws layout (bytes):
//       0: S      G*N f          (1,280,000 B)
// 1280000: P      96 float4      (wl, wr, bl+br, 0.4*att)
// 1281536: lin3   3 f
// 1281552: offsG  4*251 i        (per-quarter LOCAL CSR offsets)
// 1285568: slots  4*CAP int2     (per-quarter packed (src,dst))

// ---------------- kA: shared CSR build, one block per quarter ----------------
__global__ __launch_bounds__(512) void kA(
        const int* __restrict__ ei,
        const float* __restrict__ Wl, const float* __restrict__ bl,
        const float* __restrict__ Wr, const float* __restrict__ br,
        const float* __restrict__ att,
        float4* __restrict__ P, float* __restrict__ lin3g,
        int* __restrict__ offsG, int2* __restrict__ slots) {
    __shared__ int cnt[256], cur[256], offsL[260];
    const int tid = threadIdx.x;
    const int q = blockIdx.x;
    const int lo = q * QN;

    if (q == 0) {   // pack channel params + lin3 (block 0 only)
        if (tid < C_)
            P[tid] = make_float4(Wl[tid], Wr[tid], bl[tid] + br[tid], 0.4f * att[tid]);
        int w = tid >> 6, lane = tid & 63;
        if (w < 3) {
            float s = 0.f;
            for (int i = lane; i < C_; i += 64) {
                float a = att[i];
                float m = (w == 0) ? Wl[i] : (w == 1) ? Wr[i] : (bl[i] + br[i]);
                s += a * m;
            }
            for (int off = 32; off; off >>= 1) s += __shfl_down(s, off);
            if (lane == 0) lin3g[w] = 0.6f * s;
        }
    }
    for (int i = tid; i < 256; i += 512) cnt[i] = (i < QN) ? 1 : 0; // self-loop
    __syncthreads();

    const int4* d4 = (const int4*)(ei + E_);
    const int4* s4 = (const int4*)ei;
    for (int j = tid; j < E_ / 4; j += 512) {
        int4 d = d4[j];
        int r0 = d.x - lo, r1 = d.y - lo, r2 = d.z - lo, r3 = d.w - lo;
        if ((unsigned)r0 < (unsigned)QN) atomicAdd(&cnt[r0], 1);
        if ((unsigned)r1 < (unsigned)QN) atomicAdd(&cnt[r1], 1);
        if ((unsigned)r2 < (unsigned)QN) atomicAdd(&cnt[r2], 1);
        if ((unsigned)r3 < (unsigned)QN) atomicAdd(&cnt[r3], 1);
    }
    __syncthreads();

    if (tid < 64) {   // wave-0 shuffle scan, lane owns 4 counters
        int b4 = tid * 4;
        int a0 = cnt[b4], a1 = cnt[b4 + 1], a2 = cnt[b4 + 2], a3 = cnt[b4 + 3];
        int s1 = a0 + a1, s2 = s1 + a2, s3 = s2 + a3;
        int pre = s3;
        for (int off = 1; off < 64; off <<= 1) {
            int tv = __shfl_up(pre, off);
            if (tid >= off) pre += tv;
        }
        int base = pre - s3;
        offsL[b4] = base;          cur[b4] = base;
        offsL[b4 + 1] = base + a0; cur[b4 + 1] = base + a0;
        offsL[b4 + 2] = base + s1; cur[b4 + 2] = base + s1;
        offsL[b4 + 3] = base + s2; cur[b4 + 3] = base + s2;
    }
    __syncthreads();

    int2* sl = slots + (size_t)q * CAP;
    for (int j = tid; j < E_ / 4; j += 512) {
        int4 d = d4[j];
        int4 s = s4[j];
#define SCAT(DD, SS) { int r = (DD) - lo;                                    \
        if ((unsigned)r < (unsigned)QN) {                                    \
            int pos = atomicAdd(&cur[r], 1);                                 \
            sl[pos] = make_int2((SS), (DD)); } }
        SCAT(d.x, s.x) SCAT(d.y, s.y) SCAT(d.z, s.z) SCAT(d.w, s.w)
#undef SCAT
    }
    for (int i = tid; i < QN; i += 512) {       // self-loops
        int pos = atomicAdd(&cur[i], 1);
        sl[pos] = make_int2(lo + i, lo + i);
    }
    for (int i = tid; i <= QN; i += 512) offsG[q * (QN + 1) + i] = offsL[i];
}

// ---------------- kS: logits + softmax -> S, per (quarter, graph) ----------------
// P is read at wave-uniform global addresses -> scalar s_load path (no LDS pipe).
__global__ __launch_bounds__(512, 4) void kS(
        const float* __restrict__ x, const float4* __restrict__ P,
        const float* __restrict__ lin3g, const int* __restrict__ offsG,
        const int2* __restrict__ slots, float* __restrict__ S) {
    __shared__ float xgs[N_];
    __shared__ float L[CAP];
    __shared__ float U[CAP];
    __shared__ int offsL[QN + 1];
    const int tid = threadIdx.x;
    const int q = blockIdx.x;
    const int g = blockIdx.y;
    const int lo = q * QN;

    const float* xg = x + g * N_;
    if (tid < N_ / 4) ((float4*)xgs)[tid] = ((const float4*)xg)[tid];
    for (int i = tid; i <= QN; i += 512) offsL[i] = offsG[q * (QN + 1) + i];
    __syncthreads();
    const int cntE = offsL[QN];
    const float la = lin3g[0], lb = lin3g[1], lc = lin3g[2];
    const int2* sl = slots + (size_t)q * CAP;

    // main logit batch: e = 0.6*(u*A+v*B+Cb) + sum_c 0.4*att_c*|u*wl+v*wr+bb|
    {
        float u[EPT], v[EPT], acc[EPT];
#pragma unroll
        for (int k = 0; k < EPT; k++) {
            int p = tid + k * 512;
            int2 sd = sl[p < cntE ? p : 0];
            u[k] = xgs[sd.x]; v[k] = xgs[sd.y]; acc[k] = 0.f;
        }
#pragma unroll 8
        for (int c = 0; c < C_; c++) {
            float4 qv = P[c];                    // uniform -> s_load_dwordx4
#pragma unroll
            for (int k = 0; k < EPT; k++) {
                float wv = fmaf(u[k], qv.x, fmaf(v[k], qv.y, qv.z));
                acc[k] = fmaf(qv.w, fabsf(wv), acc[k]);
            }
        }
#pragma unroll
        for (int k = 0; k < EPT; k++) {
            int p = tid + k * 512;
            if (p < cntE) {
                L[p] = fmaf(u[k], la, fmaf(v[k], lb, lc)) + acc[k];
                U[p] = u[k];
            }
        }
    }
    for (int p = tid + 512 * EPT; p < cntE; p += 512) {  // rare overflow slots
        int2 sd = sl[p];
        float uu = xgs[sd.x], vv = xgs[sd.y], a2 = 0.f;
        for (int c = 0; c < C_; c++) {
            float4 qv = P[c];
            float wv = fmaf(uu, qv.x, fmaf(vv, qv.y, qv.z));
            a2 = fmaf(qv.w, fabsf(wv), a2);
        }
        L[p] = fmaf(uu, la, fmaf(vv, lb, lc)) + a2;
        U[p] = uu;
    }
    __syncthreads();

    // per-node branchless online softmax -> scalar S
    if (tid < QN) {
        int a = offsL[tid], b = offsL[tid + 1];
        float m = -INFINITY, den = 0.f, num = 0.f;
        for (int p = a; p < b; ++p) {
            float l = L[p], uu = U[p];
            float nm = fmaxf(m, l);
            float sc = __expf(m - nm);
            float ex = __expf(l - nm);
            den = den * sc + ex;
            num = fmaf(ex, uu, num * sc);
            m = nm;
        }
        S[g * N_ + lo + tid] = num / den;
    }
}

// ---------------- kE: pure streaming expansion ----------------
// out[gi,c] = S[gi]*Wl[c] + (bl[c]+bias[c]+pos[t,c]); t = (gi/N)%T
__global__ __launch_bounds__(256) void kE(
        const float* __restrict__ S, const float* __restrict__ Wl,
        const float* __restrict__ bl, const float* __restrict__ bias,
        float4* __restrict__ out) {
    __shared__ float4 cbT[T_][C_ / 4];
    const int tid = threadIdx.x;
    if (tid < T_ * (C_ / 4)) {
        int t = tid / (C_ / 4), c4i = tid % (C_ / 4);
        float4 v;
        float* vp = (float*)&v;
#pragma unroll
        for (int j = 0; j < 4; j++) {
            int c = c4i * 4 + j;
            int k2 = c & ~1;
            float dt = __expf(-(float)k2 * (logf(10000.0f) / (float)C_));
            float ang = (float)t * dt;
            float pe = (c & 1) ? cosf(ang) : sinf(ang);
            vp[j] = bl[c] + bias[c] + pe;
        }
        cbT[t][c4i] = v;
    }
    unsigned idx0 = blockIdx.x * 256u + tid;
    int c4 = idx0 % 24u;                       // constant per thread
    float4 wl = ((const float4*)Wl)[c4];       // registers, loaded once
    __syncthreads();
    for (unsigned idx = idx0; idx < (unsigned)TOT4; idx += KE_STRIDE) {
        unsigned gi = idx / 24u;
        unsigned t = (gi / (unsigned)N_) % (unsigned)T_;
        float s = S[gi];
        float4 cb = cbT[t][c4];
        out[idx] = make_float4(fmaf(s, wl.x, cb.x), fmaf(s, wl.y, cb.y),
                               fmaf(s, wl.z, cb.z), fmaf(s, wl.w, cb.w));
    }
}

extern "C" void kernel_launch(void* const* d_in, const int* in_sizes, int n_in,
                              void* d_out, int out_size, void* d_ws, size_t ws_size,
                              hipStream_t stream) {
    const float* x    = (const float*)d_in[0];
    const int*   ei   = (const int*)d_in[1];
    const float* Wl   = (const float*)d_in[2];
    const float* bl   = (const float*)d_in[3];
    const float* Wr   = (const float*)d_in[4];
    const float* br   = (const float*)d_in[5];
    const float* att  = (const float*)d_in[6];
    const float* bias = (const float*)d_in[7];
    float4* out = (float4*)d_out;

    char* ws = (char*)d_ws;
    float*  S     = (float*)(ws + 0);
    float4* P     = (float4*)(ws + 1280000);
    float*  lin3g = (float*)(ws + 1281536);
    int*    offsG = (int*)(ws + 1281552);
    int2*   slots = (int2*)(ws + 1285568);

    hipLaunchKernelGGL(kA, dim3(4), dim3(512), 0, stream,
                       ei, Wl, bl, Wr, br, att, P, lin3g, offsG, slots);
    hipLaunchKernelGGL(kS, dim3(4, G_), dim3(512), 0, stream,
                       x, P, lin3g, offsG, slots, S);
    hipLaunchKernelGGL(kE, dim3(KE_BLOCKS), dim3(256), 0, stream,
                       S, Wl, bl, bias, out);
}

// Round 8
// 52.064 us; speedup vs baseline: 1.7555x; 1.2820x over previous
//
#include <hip/hip_runtime.h>
#include <math.h>

#define G_ 320
#define N_ 1000
#define T_ 10
#define C_ 96
#define E_ 8000
#define QN 250          // nodes per quarter (4 quarters)
#define CAP 2816        // slot capacity per quarter (mean ~2250, >14 sigma)
#define EPT 5           // slots per thread in main logit pass

// ws layout (bytes):
//       0: P      96 float4      (wl, wr, bl+br, 0.4*att)
//    1536: lin3   3 f
//    1552: offsG  4*251 i        (per-quarter LOCAL CSR offsets)
//    5568: slots  4*CAP int2     (per-quarter packed (src,dst))

// ---------------- kA: shared CSR build, one block per quarter ----------------
__global__ __launch_bounds__(512) void kA(
        const int* __restrict__ ei,
        const float* __restrict__ Wl, const float* __restrict__ bl,
        const float* __restrict__ Wr, const float* __restrict__ br,
        const float* __restrict__ att,
        float4* __restrict__ P, float* __restrict__ lin3g,
        int* __restrict__ offsG, int2* __restrict__ slots) {
    __shared__ int cnt[256], cur[256], offsL[260];
    const int tid = threadIdx.x;
    const int q = blockIdx.x;
    const int lo = q * QN;

    if (q == 0) {   // pack channel params + lin3 (block 0 only)
        if (tid < C_)
            P[tid] = make_float4(Wl[tid], Wr[tid], bl[tid] + br[tid], 0.4f * att[tid]);
        int w = tid >> 6, lane = tid & 63;
        if (w < 3) {
            float s = 0.f;
            for (int i = lane; i < C_; i += 64) {
                float a = att[i];
                float m = (w == 0) ? Wl[i] : (w == 1) ? Wr[i] : (bl[i] + br[i]);
                s += a * m;
            }
            for (int off = 32; off; off >>= 1) s += __shfl_down(s, off);
            if (lane == 0) lin3g[w] = 0.6f * s;
        }
    }
    for (int i = tid; i < 256; i += 512) cnt[i] = (i < QN) ? 1 : 0; // self-loop
    __syncthreads();

    const int4* d4 = (const int4*)(ei + E_);
    const int4* s4 = (const int4*)ei;
    for (int j = tid; j < E_ / 4; j += 512) {
        int4 d = d4[j];
        int r0 = d.x - lo, r1 = d.y - lo, r2 = d.z - lo, r3 = d.w - lo;
        if ((unsigned)r0 < (unsigned)QN) atomicAdd(&cnt[r0], 1);
        if ((unsigned)r1 < (unsigned)QN) atomicAdd(&cnt[r1], 1);
        if ((unsigned)r2 < (unsigned)QN) atomicAdd(&cnt[r2], 1);
        if ((unsigned)r3 < (unsigned)QN) atomicAdd(&cnt[r3], 1);
    }
    __syncthreads();

    if (tid < 64) {   // wave-0 shuffle scan, lane owns 4 counters
        int b4 = tid * 4;
        int a0 = cnt[b4], a1 = cnt[b4 + 1], a2 = cnt[b4 + 2], a3 = cnt[b4 + 3];
        int s1 = a0 + a1, s2 = s1 + a2, s3 = s2 + a3;
        int pre = s3;
        for (int off = 1; off < 64; off <<= 1) {
            int tv = __shfl_up(pre, off);
            if (tid >= off) pre += tv;
        }
        int base = pre - s3;
        offsL[b4] = base;          cur[b4] = base;
        offsL[b4 + 1] = base + a0; cur[b4 + 1] = base + a0;
        offsL[b4 + 2] = base + s1; cur[b4 + 2] = base + s1;
        offsL[b4 + 3] = base + s2; cur[b4 + 3] = base + s2;
    }
    __syncthreads();

    int2* sl = slots + (size_t)q * CAP;
    for (int j = tid; j < E_ / 4; j += 512) {
        int4 d = d4[j];
        int4 s = s4[j];
#define SCAT(DD, SS) { int r = (DD) - lo;                                    \
        if ((unsigned)r < (unsigned)QN) {                                    \
            int pos = atomicAdd(&cur[r], 1);                                 \
            sl[pos] = make_int2((SS), (DD)); } }
        SCAT(d.x, s.x) SCAT(d.y, s.y) SCAT(d.z, s.z) SCAT(d.w, s.w)
#undef SCAT
    }
    for (int i = tid; i < QN; i += 512) {       // self-loops
        int pos = atomicAdd(&cur[i], 1);
        sl[pos] = make_int2(lo + i, lo + i);
    }
    for (int i = tid; i <= QN; i += 512) offsG[q * (QN + 1) + i] = offsL[i];
}

// ------- kF: logits + softmax + output expansion, per (quarter, graph) -------
// P read at wave-uniform global addresses -> scalar s_load path.
__global__ __launch_bounds__(512, 4) void kF(
        const float* __restrict__ x, const float4* __restrict__ P,
        const float* __restrict__ lin3g, const int* __restrict__ offsG,
        const int2* __restrict__ slots,
        const float* __restrict__ Wl, const float* __restrict__ bl,
        const float* __restrict__ bias, float4* __restrict__ out) {
    __shared__ float xgs[N_];
    __shared__ float L[CAP];
    __shared__ float U[CAP];
    __shared__ int offsL[QN + 1];
    __shared__ float Sloc[QN];
    __shared__ float4 wl4[C_ / 4], cb4[C_ / 4];
    const int tid = threadIdx.x;
    const int q = blockIdx.x;
    const int g = blockIdx.y;
    const int lo = q * QN;
    const int t = g % T_;

    const float* xg = x + g * N_;
    if (tid < N_ / 4) ((float4*)xgs)[tid] = ((const float4*)xg)[tid];
    for (int i = tid; i <= QN; i += 512) offsL[i] = offsG[q * (QN + 1) + i];
    if (tid < C_) {   // per-block expansion tables (wl, combined bias+pos)
        int k2 = tid & ~1;
        float dt = __expf(-(float)k2 * (logf(10000.0f) / (float)C_));
        float ang = (float)t * dt;
        float pe = (tid & 1) ? cosf(ang) : sinf(ang);
        ((float*)wl4)[tid] = Wl[tid];
        ((float*)cb4)[tid] = bl[tid] + bias[tid] + pe;
    }
    __syncthreads();
    const int cntE = offsL[QN];
    const float la = lin3g[0], lb = lin3g[1], lc = lin3g[2];
    const int2* sl = slots + (size_t)q * CAP;

    // main logit batch: e = 0.6*(u*A+v*B+Cb) + sum_c 0.4*att_c*|u*wl+v*wr+bb|
    {
        float u[EPT], v[EPT], acc[EPT];
#pragma unroll
        for (int k = 0; k < EPT; k++) {
            int p = tid + k * 512;
            int2 sd = sl[p < cntE ? p : 0];
            u[k] = xgs[sd.x]; v[k] = xgs[sd.y]; acc[k] = 0.f;
        }
#pragma unroll 8
        for (int c = 0; c < C_; c++) {
            float4 qv = P[c];                    // uniform -> s_load_dwordx4
#pragma unroll
            for (int k = 0; k < EPT; k++) {
                float wv = fmaf(u[k], qv.x, fmaf(v[k], qv.y, qv.z));
                acc[k] = fmaf(qv.w, fabsf(wv), acc[k]);
            }
        }
#pragma unroll
        for (int k = 0; k < EPT; k++) {
            int p = tid + k * 512;
            if (p < cntE) {
                L[p] = fmaf(u[k], la, fmaf(v[k], lb, lc)) + acc[k];
                U[p] = u[k];
            }
        }
    }
    for (int p = tid + 512 * EPT; p < cntE; p += 512) {  // rare overflow slots
        int2 sd = sl[p];
        float uu = xgs[sd.x], vv = xgs[sd.y], a2 = 0.f;
        for (int c = 0; c < C_; c++) {
            float4 qv = P[c];
            float wv = fmaf(uu, qv.x, fmaf(vv, qv.y, qv.z));
            a2 = fmaf(qv.w, fabsf(wv), a2);
        }
        L[p] = fmaf(uu, la, fmaf(vv, lb, lc)) + a2;
        U[p] = uu;
    }
    __syncthreads();

    // per-node branchless online softmax -> Sloc
    if (tid < QN) {
        int a = offsL[tid], b = offsL[tid + 1];
        float m = -INFINITY, den = 0.f, num = 0.f;
        for (int p = a; p < b; ++p) {
            float l = L[p], uu = U[p];
            float nm = fmaxf(m, l);
            float sc = __expf(m - nm);
            float ex = __expf(l - nm);
            den = den * sc + ex;
            num = fmaf(ex, uu, num * sc);
            m = nm;
        }
        Sloc[tid] = num / den;
    }
    __syncthreads();

    // expansion: contiguous 250x24-float4 slab; incremental i/24 (512=21*24+8)
    float4* out4 = out + (size_t)(g * N_ + lo) * (C_ / 4);
    int node = tid / 24, c4 = tid % 24;
    for (int i = tid; i < QN * (C_ / 4); i += 512) {
        float s = Sloc[node];
        float4 wv = wl4[c4], cb = cb4[c4];
        out4[i] = make_float4(fmaf(s, wv.x, cb.x), fmaf(s, wv.y, cb.y),
                              fmaf(s, wv.z, cb.z), fmaf(s, wv.w, cb.w));
        int c4n = c4 + 8;
        int carry = (c4n >= 24) ? 1 : 0;
        node += 21 + carry;
        c4 = c4n - (carry ? 24 : 0);
    }
}

extern "C" void kernel_launch(void* const* d_in, const int* in_sizes, int n_in,
                              void* d_out, int out_size, void* d_ws, size_t ws_size,
                              hipStream_t stream) {
    const float* x    = (const float*)d_in[0];
    const int*   ei   = (const int*)d_in[1];
    const float* Wl   = (const float*)d_in[2];
    const float* bl   = (const float*)d_in[3];
    const float* Wr   = (const float*)d_in[4];
    const float* br   = (const float*)d_in[5];
    const float* att  = (const float*)d_in[6];
    const float* bias = (const float*)d_in[7];
    float4* out = (float4*)d_out;

    char* ws = (char*)d_ws;
    float4* P     = (float4*)(ws + 0);
    float*  lin3g = (float*)(ws + 1536);
    int*    offsG = (int*)(ws + 1552);
    int2*   slots = (int2*)(ws + 5568);

    hipLaunchKernelGGL(kA, dim3(4), dim3(512), 0, stream,
                       ei, Wl, bl, Wr, br, att, P, lin3g, offsG, slots);
    hipLaunchKernelGGL(kF, dim3(4, G_), dim3(512), 0, stream,
                       x, P, lin3g, offsG, slots, Wl, bl, bias, out);
}